// Round 9
// baseline (152.144 us; speedup 1.0000x reference)
//
#include <hip/hip_runtime.h>
#include <hip/hip_bf16.h>

#define GATE 512
#define MROWS 256
#define NTOT 120581
#define PHK 32            // K per LDS phase (16 phases)

typedef __attribute__((ext_vector_type(8))) short short8;   // 8 bf16
typedef __attribute__((ext_vector_type(4))) float  f32x4;

struct GemmParams {
    const float* W[10];
    const float* p[10];
    const float* bias[10];
};

__device__ __forceinline__ short bf16bits(float x) {
    __hip_bfloat16 h = __float2bfloat16(x);   // RTNE
    return *reinterpret_cast<short*>(&h);
}

__global__ void emb_to_bf16(const float* __restrict__ emb,
                            unsigned short* __restrict__ o) {
    int i = (blockIdx.x * blockDim.x + threadIdx.x) * 8;
    f32x4 a = *(const f32x4*)(emb + i);
    f32x4 b = *(const f32x4*)(emb + i + 4);
    short8 r;
#pragma unroll
    for (int j = 0; j < 4; ++j) { r[j] = bf16bits(a[j]); r[4 + j] = bf16bits(b[j]); }
    *(short8*)(o + i) = r;
}

// Block: 256 rows x 64 cols (W fetched by exactly one block).
// Waves as 2M x 2N: wave(wm,wn) = rows [wm*128,+128) x cols [wn*32,+32).
// A staged in LDS (lgkm domain) double-buffered at K-phase 32 (32 KB -> 4
// blocks/CU); B streamed from HBM one phase ahead (vmcnt counted; each
// barrier only drains loads issued a full compute-phase earlier).
// Swizzle: ROUND-2-VERIFIED slot = lg ^ ((lr>>1)&3) -> with 64 B row stride
// the bank-group = (lr&1, (lr>>1)&3) = 3 independent lr bits = 8 groups x 2
// lanes = conflict-free (round 8's lr&3 variant collapsed to 4 groups, 3.86M
// conflict cycles).
__global__ __launch_bounds__(256, 4) void gate_gemm(GemmParams P,
                                                    const unsigned short* __restrict__ embw,
                                                    float* __restrict__ out)
{
    constexpr int kStarts[11] = {0, 1728, 1792, 38656, 38720, 75584,
                                 75648, 112512, 112576, 120576, 120581};
    __shared__ unsigned short Atile[2][MROWS * PHK];   // 2 x 16 KB

    const int t    = threadIdx.x;
    const int lane = t & 63;
    const int wave = t >> 6;
    const int wm   = wave >> 1;   // M half
    const int wn   = wave & 1;    // N half
    const int lr   = lane & 15;   // frag col (B/C) / frag row (A)
    const int lg   = lane >> 4;   // k-group / C row-group

    // Per-lane column metadata, 2 N-fragments (cols wn*32 + nf*16 + lr)
    const float* wrow[2];
    float pv[2], bv[2];
    bool  valid[2];
    int   ncol[2];
#pragma unroll
    for (int nf = 0; nf < 2; ++nf) {
        int n = blockIdx.x * 64 + wn * 32 + nf * 16 + lr;
        ncol[nf]  = n;
        valid[nf] = n < NTOT;
        int nc = valid[nf] ? n : NTOT - 1;
        int tt = 0;
#pragma unroll
        for (int i = 1; i < 10; ++i) tt += (nc >= kStarts[i]);
        int r = nc - kStarts[tt];
        wrow[nf] = P.W[tt] + (size_t)r * GATE + lg * 8;
        pv[nf]   = P.p[tt][r];
        bv[nf]   = P.bias[tt][r];
    }

    // ---- A staging: pre-swizzled global source, linear LDS dest.
    // LDS 16B-unit u: row = u>>2, slotw = u&3; holds
    // embw[row][p*32 + (slotw ^ ((row>>1)&3))*8 .. +8].
    // row = i*64 + (t>>2) -> (row>>1)&3 = (t>>3)&3 (i*32 ≡ 0 mod 4).
    const int srow0 = t >> 2;
    const int sslot = (t & 3) ^ ((t >> 3) & 3);    // round-2-verified
    const unsigned short* asrc0 = embw + (size_t)srow0 * GATE + sslot * 8;

    auto stage = [&](int buf, int p) {
#pragma unroll
        for (int i = 0; i < 4; ++i) {
            const unsigned short* src = asrc0 + (size_t)i * 64 * GATE + p * PHK;
            unsigned short* dst = &Atile[buf][(size_t)(i * 256 + t) * 8];
            __builtin_amdgcn_global_load_lds(
                (const __attribute__((address_space(1))) void*)src,
                (__attribute__((address_space(3))) void*)dst, 16, 0, 0);
        }
    };

    // A read: row = wm*128 + mf*16 + lr -> (row>>1)&3 = (lr>>1)&3.
    const int axor  = (lr >> 1) & 3;               // round-2-verified
    const int abase = (wm * 128 + lr) * PHK;       // ushort idx; + mf*16*PHK + slot*8

    f32x4 acc[8][2];
#pragma unroll
    for (int i = 0; i < 8; ++i)
#pragma unroll
        for (int j = 0; j < 2; ++j) acc[i][j] = (f32x4){0.f, 0.f, 0.f, 0.f};

    f32x4 Bc[2][2], Bn[2][2];
    auto loadB = [&](f32x4 (&B)[2][2], int p) {
#pragma unroll
        for (int nf = 0; nf < 2; ++nf) {
            B[nf][0] = *(const f32x4*)(wrow[nf] + p * PHK);
            B[nf][1] = *(const f32x4*)(wrow[nf] + p * PHK + 4);
        }
    };

    // Prologue
    stage(0, 0);
    loadB(Bc, 0);
    __syncthreads();

    int buf = 0;
#pragma unroll
    for (int p = 0; p < 16; ++p) {
        if (p < 15) {
            stage(buf ^ 1, p + 1);   // A for next phase (lands during this compute)
            loadB(Bn, p + 1);        // B for next phase (counted wait, never drained cold)
        }

        short8 bfrag[2];
#pragma unroll
        for (int nf = 0; nf < 2; ++nf)
#pragma unroll
            for (int j = 0; j < 4; ++j) {
                bfrag[nf][j]     = bf16bits(Bc[nf][0][j]);
                bfrag[nf][4 + j] = bf16bits(Bc[nf][1][j]);
            }

#pragma unroll
        for (int mf = 0; mf < 8; ++mf) {
            short8 af = *(const short8*)(&Atile[buf][abase + mf * 16 * PHK + (lg ^ axor) * 8]);
            acc[mf][0] = __builtin_amdgcn_mfma_f32_16x16x32_bf16(af, bfrag[0], acc[mf][0], 0, 0, 0);
            acc[mf][1] = __builtin_amdgcn_mfma_f32_16x16x32_bf16(af, bfrag[1], acc[mf][1], 0, 0, 0);
        }

        if (p < 15) {
#pragma unroll
            for (int nf = 0; nf < 2; ++nf) { Bc[nf][0] = Bn[nf][0]; Bc[nf][1] = Bn[nf][1]; }
            __syncthreads();   // drains stage/loadB issued a full phase ago
            buf ^= 1;
        }
    }

    // Epilogue: sigmoid(x+b)*p. C/D map: col = lane&15, row = (lane>>4)*4 + reg.
    // nf innermost: lane-group writes 2x16 = 128 B contiguous per row; the two
    // wn-waves merge to 256 B/row in L2.
#pragma unroll
    for (int mf = 0; mf < 8; ++mf) {
#pragma unroll
        for (int q = 0; q < 4; ++q) {
            const int m = wm * 128 + mf * 16 + lg * 4 + q;
            float* orow = out + (size_t)m * NTOT;
#pragma unroll
            for (int nf = 0; nf < 2; ++nf) {
                if (!valid[nf]) continue;
                float x   = acc[mf][nf][q] + bv[nf];
                float e   = __expf(-x);
                float eta = __builtin_amdgcn_rcpf(1.0f + e);
                orow[ncol[nf]] = eta * pv[nf];
            }
        }
    }
}

extern "C" void kernel_launch(void* const* d_in, const int* in_sizes, int n_in,
                              void* d_out, int out_size, void* d_ws, size_t ws_size,
                              hipStream_t stream) {
    const float* emb = (const float*)d_in[0];
    GemmParams P;
    for (int i = 0; i < 10; ++i) {
        P.p[i]    = (const float*)d_in[1 + 3 * i];
        P.W[i]    = (const float*)d_in[2 + 3 * i];
        P.bias[i] = (const float*)d_in[3 + 3 * i];
    }

    unsigned short* embw = (unsigned short*)d_ws;   // 256 KB, L2-resident
    emb_to_bf16<<<(MROWS * GATE) / (256 * 8), 256, 0, stream>>>(emb, embw);

    int nblocks = (NTOT + 63) / 64;   // 1885
    gate_gemm<<<nblocks, 256, 0, stream>>>(P, embw, (float*)d_out);
}

// Round 10
// 128.213 us; speedup vs baseline: 1.1867x; 1.1867x over previous
//
#include <hip/hip_runtime.h>
#include <hip/hip_bf16.h>

#define GATE 512
#define MROWS 256
#define NTOT 120581
#define PHK 64            // K per LDS phase (8 phases)

typedef __attribute__((ext_vector_type(8))) short short8;   // 8 bf16
typedef __attribute__((ext_vector_type(4))) float  f32x4;

struct GemmParams {
    const float* W[10];
    const float* p[10];
    const float* bias[10];
};

__device__ __forceinline__ short bf16bits(float x) {
    __hip_bfloat16 h = __float2bfloat16(x);   // RTNE
    return *reinterpret_cast<short*>(&h);
}

__global__ void emb_to_bf16(const float* __restrict__ emb,
                            unsigned short* __restrict__ o) {
    int i = (blockIdx.x * blockDim.x + threadIdx.x) * 8;
    f32x4 a = *(const f32x4*)(emb + i);
    f32x4 b = *(const f32x4*)(emb + i + 4);
    short8 r;
#pragma unroll
    for (int j = 0; j < 4; ++j) { r[j] = bf16bits(a[j]); r[4 + j] = bf16bits(b[j]); }
    *(short8*)(o + i) = r;
}

// Block: 256 rows x 64 cols (W fetched by exactly one block).
// Waves 2M x 2N: wave(wm,wn) = rows [wm*128,+128) x cols [wn*32,+32)
//   -> A frag feeds 2 MFMAs, LDS read traffic halved vs 1Nx4.
// A: LDS double-buffered, K-phase 64 (round-7-verified conflict-free swizzle).
// B: 3-set rotating register pipeline, issued 2 phases ahead.
// Phase end: COUNTED vmcnt (T4) + raw s_barrier — never drains the
// just-issued B prefetch (only prologue/last phases hit vmcnt(0)).
__global__ __launch_bounds__(256, 2) void gate_gemm(GemmParams P,
                                                    const unsigned short* __restrict__ embw,
                                                    float* __restrict__ out)
{
    constexpr int kStarts[11] = {0, 1728, 1792, 38656, 38720, 75584,
                                 75648, 112512, 112576, 120576, 120581};
    __shared__ unsigned short Atile[2][MROWS * PHK];   // 2 x 32 KB

    const int t    = threadIdx.x;
    const int lane = t & 63;
    const int wave = t >> 6;
    const int wm   = wave >> 1;   // M half
    const int wn   = wave & 1;    // N half
    const int lr   = lane & 15;   // frag col (B/C) / frag row (A)
    const int lg   = lane >> 4;   // k-group / C row-group

    // Per-lane column metadata, 2 N-fragments (cols wn*32 + nf*16 + lr)
    const float* wrow[2];
    float pv[2], bv[2];
    bool  valid[2];
    int   ncol[2];
#pragma unroll
    for (int nf = 0; nf < 2; ++nf) {
        int n = blockIdx.x * 64 + wn * 32 + nf * 16 + lr;
        ncol[nf]  = n;
        valid[nf] = n < NTOT;
        int nc = valid[nf] ? n : NTOT - 1;
        int tt = 0;
#pragma unroll
        for (int i = 1; i < 10; ++i) tt += (nc >= kStarts[i]);
        int r = nc - kStarts[tt];
        wrow[nf] = P.W[tt] + (size_t)r * GATE + lg * 8;
        pv[nf]   = P.p[tt][r];
        bv[nf]   = P.bias[tt][r];
    }

    // ---- A staging (round-7-verified): pre-swizzled global source, linear LDS dest.
    // 16B-unit u = i*256 + t: row = i*32 + (t>>3), slotw = t&7;
    // holds embw[row][p*64 + ((slotw ^ (row&7))*8) .. +8].
    const int srow0 = t >> 3;
    const int sslot = (t & 7) ^ ((t >> 3) & 7);
    const unsigned short* asrc0 = embw + (size_t)srow0 * GATE + sslot * 8;

    auto stage = [&](int buf, int p) {
#pragma unroll
        for (int i = 0; i < 8; ++i) {
            const unsigned short* src = asrc0 + (size_t)i * 32 * GATE + p * PHK;
            unsigned short* dst = &Atile[buf][(size_t)(i * 256 + t) * 8];
            __builtin_amdgcn_global_load_lds(
                (const __attribute__((address_space(1))) void*)src,
                (__attribute__((address_space(3))) void*)dst, 16, 0, 0);
        }
    };

    // A read: row = wm*128 + mf*16 + lr; k-slot (ss*4+lg) stored at slot^(row&7).
    const int axor  = lr & 7;
    const int abase = (wm * 128 + lr) * PHK;   // ushort idx

    f32x4 acc[8][2];
#pragma unroll
    for (int i = 0; i < 8; ++i)
#pragma unroll
        for (int j = 0; j < 2; ++j) acc[i][j] = (f32x4){0.f, 0.f, 0.f, 0.f};

    // B register pipeline: Bs[rot][ss*4 + nf*2 + c], all indices compile-time
    // after full unroll. 8 x f32x4 per set = one phase (K=64) per lane.
    f32x4 Bs[3][8];
    auto loadB = [&](f32x4 (&B)[8], int p) {
#pragma unroll
        for (int ss = 0; ss < 2; ++ss)
#pragma unroll
            for (int nf = 0; nf < 2; ++nf) {
                B[ss * 4 + nf * 2 + 0] = *(const f32x4*)(wrow[nf] + p * PHK + ss * 32);
                B[ss * 4 + nf * 2 + 1] = *(const f32x4*)(wrow[nf] + p * PHK + ss * 32 + 4);
            }
    };

    // Prologue: phase-0 A, B for phases 0 and 1; full drain once.
    stage(0, 0);
    loadB(Bs[0], 0);
    loadB(Bs[1], 1);
    __syncthreads();

#pragma unroll
    for (int p = 0; p < 8; ++p) {
        const int buf = p & 1;
        if (p + 1 < 8) stage(buf ^ 1, p + 1);        // A next phase  [8 vmem ops]
        if (p + 2 < 8) loadB(Bs[(p + 2) % 3], p + 2); // B 2 ahead     [8 vmem ops]

#pragma unroll
        for (int ss = 0; ss < 2; ++ss) {
            short8 bfrag[2];
#pragma unroll
            for (int nf = 0; nf < 2; ++nf) {
                const f32x4 lo = Bs[p % 3][ss * 4 + nf * 2 + 0];
                const f32x4 hi = Bs[p % 3][ss * 4 + nf * 2 + 1];
#pragma unroll
                for (int j = 0; j < 4; ++j) {
                    bfrag[nf][j]     = bf16bits(lo[j]);
                    bfrag[nf][4 + j] = bf16bits(hi[j]);
                }
            }
#pragma unroll
            for (int mf = 0; mf < 8; ++mf) {
                short8 af = *(const short8*)(
                    &Atile[buf][abase + mf * 16 * PHK + (((ss * 4 + lg) ^ axor)) * 8]);
                acc[mf][0] = __builtin_amdgcn_mfma_f32_16x16x32_bf16(af, bfrag[0], acc[mf][0], 0, 0, 0);
                acc[mf][1] = __builtin_amdgcn_mfma_f32_16x16x32_bf16(af, bfrag[1], acc[mf][1], 0, 0, 0);
            }
        }

        if (p < 7) {
            // Counted wait: outstanding (issue order) = [B_{p+1}, S_{p+1}, B_{p+2}].
            // vmcnt(8) completes own stage + next-phase B, leaves B_{p+2} in flight.
            if (p < 6) asm volatile("s_waitcnt vmcnt(8)" ::: "memory");
            else       asm volatile("s_waitcnt vmcnt(0)" ::: "memory");
            __builtin_amdgcn_s_barrier();
            __builtin_amdgcn_sched_barrier(0);
        }
    }

    // Epilogue: sigmoid(x+b)*p. C/D map: col = lane&15, row = (lane>>4)*4 + reg.
    // nf innermost (measured write amp 1.08 in this geometry).
#pragma unroll
    for (int mf = 0; mf < 8; ++mf) {
#pragma unroll
        for (int q = 0; q < 4; ++q) {
            const int m = wm * 128 + mf * 16 + lg * 4 + q;
            float* orow = out + (size_t)m * NTOT;
#pragma unroll
            for (int nf = 0; nf < 2; ++nf) {
                if (!valid[nf]) continue;
                float x   = acc[mf][nf][q] + bv[nf];
                float e   = __expf(-x);
                float eta = __builtin_amdgcn_rcpf(1.0f + e);
                orow[ncol[nf]] = eta * pv[nf];
            }
        }
    }
}

extern "C" void kernel_launch(void* const* d_in, const int* in_sizes, int n_in,
                              void* d_out, int out_size, void* d_ws, size_t ws_size,
                              hipStream_t stream) {
    const float* emb = (const float*)d_in[0];
    GemmParams P;
    for (int i = 0; i < 10; ++i) {
        P.p[i]    = (const float*)d_in[1 + 3 * i];
        P.W[i]    = (const float*)d_in[2 + 3 * i];
        P.bias[i] = (const float*)d_in[3 + 3 * i];
    }

    unsigned short* embw = (unsigned short*)d_ws;   // 256 KB, L2-resident
    emb_to_bf16<<<(MROWS * GATE) / (256 * 8), 256, 0, stream>>>(emb, embw);

    int nblocks = (NTOT + 63) / 64;   // 1885
    gate_gemm<<<nblocks, 256, 0, stream>>>(P, embw, (float*)d_out);
}

// Round 11
// 119.291 us; speedup vs baseline: 1.2754x; 1.0748x over previous
//
#include <hip/hip_runtime.h>
#include <hip/hip_bf16.h>

#define GATE 512
#define MROWS 256
#define NTOT 120581
#define CH 16            // A rows per chunk
#define NCH 16           // chunks (16 x 16 = 256 rows)

typedef __attribute__((ext_vector_type(8))) short short8;   // 8 bf16
typedef __attribute__((ext_vector_type(4))) float  f32x4;

struct GemmParams {
    const float* W[10];
    const float* p[10];
    const float* bias[10];
};

__device__ __forceinline__ short bf16bits(float x) {
    __hip_bfloat16 h = __float2bfloat16(x);   // RTNE
    return *reinterpret_cast<short*>(&h);
}

__global__ void emb_to_bf16(const float* __restrict__ emb,
                            unsigned short* __restrict__ o) {
    int i = (blockIdx.x * blockDim.x + threadIdx.x) * 8;
    f32x4 a = *(const f32x4*)(emb + i);
    f32x4 b = *(const f32x4*)(emb + i + 4);
    short8 r;
#pragma unroll
    for (int j = 0; j < 4; ++j) { r[j] = bf16bits(a[j]); r[4 + j] = bf16bits(b[j]); }
    *(short8*)(o + i) = r;
}

// Block: 256 rows x 64 cols; wave w owns cols [w*16,+16) (W fetched once, by
// exactly one block; measured write amp 1.08 in this store geometry).
// KEY CHANGE vs r7-r10: B (W cols) is loaded ENTIRELY in the prologue into
// 64 VGPR of bf16 -> the main loop has ZERO HBM reads. A streams through LDS
// in 16-row full-K chunks from the L2-resident embw (256 KB). Each
// __syncthreads drains only L2-hot stage ops issued a full compute earlier
// (+ chunk-old store acks) -> no exposed ~900cyc HBM waits anywhere.
__global__ __launch_bounds__(256) void gate_gemm(GemmParams P,
                                                 const unsigned short* __restrict__ embw,
                                                 float* __restrict__ out)
{
    constexpr int kStarts[11] = {0, 1728, 1792, 38656, 38720, 75584,
                                 75648, 112512, 112576, 120576, 120581};
    __shared__ unsigned short Atile[2][CH * GATE];   // 2 x 16 KB

    const int t    = threadIdx.x;
    const int lane = t & 63;
    const int wave = t >> 6;
    const int lr   = lane & 15;   // frag col (B/C) / frag row (A)
    const int lg   = lane >> 4;   // k-group / C row-group

    // This lane's single output column
    const int  n     = blockIdx.x * 64 + wave * 16 + lr;
    const bool valid = n < NTOT;
    const int  nc    = valid ? n : NTOT - 1;
    int tt = 0;
#pragma unroll
    for (int i = 1; i < 10; ++i) tt += (nc >= kStarts[i]);
    const int rr = nc - kStarts[tt];
    const float* wrow = P.W[tt] + (size_t)rr * GATE + lg * 8;
    const float pv = P.p[tt][rr];
    const float bv = P.bias[tt][rr];

    // ---- A staging: chunk c = rows [c*16, +16), full K, swizzled.
    // LDS 16B-unit (row, slotw) holds embw[c*16+row][(slotw ^ (row&7))*8 ..+8].
    // Thread (i, wave, lane): unit = i*256 + t -> row = i*4 + wave, slotw = lane.
    // Wave-uniform dst base + lane*16 (global_load_lds requirement) ✓.
    auto stage = [&](int buf, int c) {
#pragma unroll
        for (int i = 0; i < 4; ++i) {
            const int rl = i * 4 + wave;
            const unsigned short* src =
                embw + (size_t)(c * CH + rl) * GATE + ((lane ^ (rl & 7)) * 8);
            unsigned short* dst = &Atile[buf][(size_t)(i * 256 + t) * 8];
            __builtin_amdgcn_global_load_lds(
                (const __attribute__((address_space(1))) void*)src,
                (__attribute__((address_space(3))) void*)dst, 16, 0, 0);
        }
    };

    stage(0, 0);   // chunk 0 while B prologue streams

    // ---- B prologue: whole-K B for this lane's column -> bf16 registers.
    // 32 x dwordx4, fully coalesced (per lr, the 4 lg lanes cover full 128 B
    // lines). 4 batches of 8 to bound raw-f32 register pressure.
    short8 Bbf[16];
#pragma unroll
    for (int b = 0; b < 4; ++b) {
        f32x4 raw[8];
#pragma unroll
        for (int j = 0; j < 4; ++j) {
            raw[j * 2 + 0] = *(const f32x4*)(wrow + (b * 4 + j) * 32);
            raw[j * 2 + 1] = *(const f32x4*)(wrow + (b * 4 + j) * 32 + 4);
        }
#pragma unroll
        for (int j = 0; j < 4; ++j) {
            short8 bb;
#pragma unroll
            for (int q = 0; q < 4; ++q) {
                bb[q]     = bf16bits(raw[j * 2][q]);
                bb[4 + q] = bf16bits(raw[j * 2 + 1][q]);
            }
            Bbf[b * 4 + j] = bb;
        }
    }

    __syncthreads();   // chunk-0 A ready (B already consumed into regs)

    int buf = 0;
#pragma unroll
    for (int c = 0; c < NCH; ++c) {
        if (c + 1 < NCH) stage(buf ^ 1, c + 1);   // L2-hot, lands during compute

        // Compute chunk: 16 dependent MFMAs into one f32x4 (cross-wave TLP
        // covers the chain; LDS read is the chip-wide serial resource).
        f32x4 acc = (f32x4){0.f, 0.f, 0.f, 0.f};
#pragma unroll
        for (int ks = 0; ks < 16; ++ks) {
            const int slot = (ks * 4 + lg) ^ (lr & 7);   // r7-verified family
            short8 af = *(const short8*)(&Atile[buf][lr * GATE + slot * 8]);
            acc = __builtin_amdgcn_mfma_f32_16x16x32_bf16(af, Bbf[ks], acc, 0, 0, 0);
        }

        __syncthreads();   // drains: stage(c+1) (L2, issued ~16 MFMA ago) +
                           // stores of chunk c-1 (issued a full chunk ago)

        // Stores AFTER the barrier: fire-and-forget, acked by next barrier.
        if (valid) {
            float* ocol = out + n;
            const int m0 = c * CH + lg * 4;
#pragma unroll
            for (int q = 0; q < 4; ++q) {
                float x   = acc[q] + bv;
                float e   = __expf(-x);
                float eta = __builtin_amdgcn_rcpf(1.0f + e);
                ocol[(size_t)(m0 + q) * NTOT] = eta * pv;
            }
        }
        buf ^= 1;
    }
}

extern "C" void kernel_launch(void* const* d_in, const int* in_sizes, int n_in,
                              void* d_out, int out_size, void* d_ws, size_t ws_size,
                              hipStream_t stream) {
    const float* emb = (const float*)d_in[0];
    GemmParams P;
    for (int i = 0; i < 10; ++i) {
        P.p[i]    = (const float*)d_in[1 + 3 * i];
        P.W[i]    = (const float*)d_in[2 + 3 * i];
        P.bias[i] = (const float*)d_in[3 + 3 * i];
    }

    unsigned short* embw = (unsigned short*)d_ws;   // 256 KB, L2-resident
    emb_to_bf16<<<(MROWS * GATE) / (256 * 8), 256, 0, stream>>>(emb, embw);

    int nblocks = (NTOT + 63) / 64;   // 1885
    gate_gemm<<<nblocks, 256, 0, stream>>>(P, embw, (float*)d_out);
}

// Round 12
// 118.134 us; speedup vs baseline: 1.2879x; 1.0098x over previous
//
#include <hip/hip_runtime.h>
#include <hip/hip_bf16.h>

#define GATE 512
#define MROWS 256
#define NTOT 120581
#define CH 16            // A rows per chunk
#define NCH 16           // chunks (16 x 16 = 256 rows)

typedef __attribute__((ext_vector_type(8))) short short8;   // 8 bf16
typedef __attribute__((ext_vector_type(4))) float  f32x4;

struct GemmParams {
    const float* W[10];
    const float* p[10];
    const float* bias[10];
};

__device__ __forceinline__ short bf16bits(float x) {
    __hip_bfloat16 h = __float2bfloat16(x);   // RTNE
    return *reinterpret_cast<short*>(&h);
}

__global__ void emb_to_bf16(const float* __restrict__ emb,
                            unsigned short* __restrict__ o) {
    int i = (blockIdx.x * blockDim.x + threadIdx.x) * 8;
    f32x4 a = *(const f32x4*)(emb + i);
    f32x4 b = *(const f32x4*)(emb + i + 4);
    short8 r;
#pragma unroll
    for (int j = 0; j < 4; ++j) { r[j] = bf16bits(a[j]); r[4 + j] = bf16bits(b[j]); }
    *(short8*)(o + i) = r;
}

// Block: 256 rows x 64 cols; wave w owns cols [w*16,+16) (W fetched once by
// exactly one block; store amp 1.08 measured).
// B: whole-K loaded in prologue -> bf16 regs, PINNED with opaque asm so the
//    compiler cannot rematerialize the loads (round 11: VGPR=56 proved it
//    re-loaded B per chunk). Main loop then truly has zero HBM reads.
// A: 16-row full-K chunks double-buffered through LDS from L2-resident embw.
// Sync: counted vmcnt + raw s_barrier (T4) -- waits cover ONLY the stage ops
//    (4 newest-but-stores), stores ride across barriers un-drained.
__global__ __launch_bounds__(256, 4) void gate_gemm(GemmParams P,
                                                    const unsigned short* __restrict__ embw,
                                                    float* __restrict__ out)
{
    constexpr int kStarts[11] = {0, 1728, 1792, 38656, 38720, 75584,
                                 75648, 112512, 112576, 120576, 120581};
    __shared__ unsigned short Atile[2][CH * GATE];   // 2 x 16 KB

    const int t    = threadIdx.x;
    const int lane = t & 63;
    const int wave = t >> 6;
    const int lr   = lane & 15;   // frag col (B/C) / frag row (A)
    const int lg   = lane >> 4;   // k-group / C row-group

    // This lane's single output column
    const int  n     = blockIdx.x * 64 + wave * 16 + lr;
    const bool valid = n < NTOT;
    const int  nc    = valid ? n : NTOT - 1;
    int tt = 0;
#pragma unroll
    for (int i = 1; i < 10; ++i) tt += (nc >= kStarts[i]);
    const int rr = nc - kStarts[tt];
    const float* wrow = P.W[tt] + (size_t)rr * GATE + lg * 8;
    const float pv = P.p[tt][rr];
    const float bv = P.bias[tt][rr];

    // ---- A staging: chunk c = rows [c*16,+16), full K, swizzled.
    // LDS 16B-unit (row, slotw=lane) holds embw[c*16+row][(lane ^ (row&7))*8 ..+8].
    auto stage = [&](int buf, int c) {
#pragma unroll
        for (int i = 0; i < 4; ++i) {
            const int rl = i * 4 + wave;
            const unsigned short* src =
                embw + (size_t)(c * CH + rl) * GATE + ((lane ^ (rl & 7)) * 8);
            unsigned short* dst = &Atile[buf][(size_t)(i * 256 + t) * 8];
            __builtin_amdgcn_global_load_lds(
                (const __attribute__((address_space(1))) void*)src,
                (__attribute__((address_space(3))) void*)dst, 16, 0, 0);
        }
    };

    stage(0, 0);   // chunk 0 streams while B prologue runs

    // ---- B prologue: whole-K B for this lane's column -> 16 x short8 (64 VGPR).
    short8 Bbf[16];
#pragma unroll
    for (int b = 0; b < 4; ++b) {
        f32x4 raw[8];
#pragma unroll
        for (int j = 0; j < 4; ++j) {
            raw[j * 2 + 0] = *(const f32x4*)(wrow + (b * 4 + j) * 32);
            raw[j * 2 + 1] = *(const f32x4*)(wrow + (b * 4 + j) * 32 + 4);
        }
#pragma unroll
        for (int j = 0; j < 4; ++j) {
            short8 bb;
#pragma unroll
            for (int q = 0; q < 4; ++q) {
                bb[q]     = bf16bits(raw[j * 2][q]);
                bb[4 + q] = bf16bits(raw[j * 2 + 1][q]);
            }
            Bbf[b * 4 + j] = bb;
        }
    }
    // PIN: make each Bbf opaque -> compiler must keep them resident (no remat).
#pragma unroll
    for (int i = 0; i < 16; ++i)
        asm volatile("" : "+v"(Bbf[i]));

    // Prologue sync: B converts already forced their own waits; drain stage(0).
    asm volatile("s_waitcnt vmcnt(0)" ::: "memory");
    __builtin_amdgcn_s_barrier();

#pragma unroll
    for (int c = 0; c < NCH; ++c) {
        const int buf = c & 1;
        if (c + 1 < NCH) stage(buf ^ 1, c + 1);   // 4 VMEM, L2-hot

        // Two parallel 8-deep MFMA chains (halve dependent latency).
        f32x4 acc0 = (f32x4){0.f, 0.f, 0.f, 0.f};
        f32x4 acc1 = (f32x4){0.f, 0.f, 0.f, 0.f};
#pragma unroll
        for (int ks = 0; ks < 16; ++ks) {
            const int slot = (ks * 4 + lg) ^ (lr & 7);
            short8 af = *(const short8*)(&Atile[buf][lr * GATE + slot * 8]);
            if (ks & 1) acc1 = __builtin_amdgcn_mfma_f32_16x16x32_bf16(af, Bbf[ks], acc1, 0, 0, 0);
            else        acc0 = __builtin_amdgcn_mfma_f32_16x16x32_bf16(af, Bbf[ks], acc0, 0, 0, 0);
        }

        // Stores issued BEFORE the wait; vmcnt(4) keeps them in flight.
        if (valid) {
            float* ocol = out + n;
            const int m0 = c * CH + lg * 4;
#pragma unroll
            for (int q = 0; q < 4; ++q) {
                float x   = acc0[q] + acc1[q] + bv;
                float e   = __expf(-x);
                float eta = __builtin_amdgcn_rcpf(1.0f + e);
                ocol[(size_t)(m0 + q) * NTOT] = eta * pv;
            }
        }

        if (c + 1 < NCH) {
            // Outstanding (issue order): [old stores][stage(c+1):4][stores(c):4].
            // vmcnt in-order -> (4) retires everything through stage(c+1),
            // leaves this chunk's stores in flight.
            asm volatile("s_waitcnt vmcnt(4)" ::: "memory");
            __builtin_amdgcn_s_barrier();
            __builtin_amdgcn_sched_barrier(0);
        }
    }
}

extern "C" void kernel_launch(void* const* d_in, const int* in_sizes, int n_in,
                              void* d_out, int out_size, void* d_ws, size_t ws_size,
                              hipStream_t stream) {
    const float* emb = (const float*)d_in[0];
    GemmParams P;
    for (int i = 0; i < 10; ++i) {
        P.p[i]    = (const float*)d_in[1 + 3 * i];
        P.W[i]    = (const float*)d_in[2 + 3 * i];
        P.bias[i] = (const float*)d_in[3 + 3 * i];
    }

    unsigned short* embw = (unsigned short*)d_ws;   // 256 KB, L2-resident
    emb_to_bf16<<<(MROWS * GATE) / (256 * 8), 256, 0, stream>>>(emb, embw);

    int nblocks = (NTOT + 63) / 64;   // 1885
    gate_gemm<<<nblocks, 256, 0, stream>>>(P, embw, (float*)d_out);
}

// Round 13
// 117.956 us; speedup vs baseline: 1.2898x; 1.0015x over previous
//
#include <hip/hip_runtime.h>
#include <hip/hip_bf16.h>

#define GATE 512
#define MROWS 256
#define NTOT 120581
#define CH 16            // A rows per chunk
#define NCH 16           // chunks (16 x 16 = 256 rows)

typedef __attribute__((ext_vector_type(8))) short short8;   // 8 bf16
typedef __attribute__((ext_vector_type(4))) float  f32x4;

struct GemmParams {
    const float* W[10];
    const float* p[10];
    const float* bias[10];
};

__device__ __forceinline__ short bf16bits(float x) {
    __hip_bfloat16 h = __float2bfloat16(x);   // RTNE
    return *reinterpret_cast<short*>(&h);
}

__global__ void emb_to_bf16(const float* __restrict__ emb,
                            unsigned short* __restrict__ o) {
    int i = (blockIdx.x * blockDim.x + threadIdx.x) * 8;
    f32x4 a = *(const f32x4*)(emb + i);
    f32x4 b = *(const f32x4*)(emb + i + 4);
    short8 r;
#pragma unroll
    for (int j = 0; j < 4; ++j) { r[j] = bf16bits(a[j]); r[4 + j] = bf16bits(b[j]); }
    *(short8*)(o + i) = r;
}

// Block: 256 rows x 64 cols; wave w owns cols [w*16,+16) (W fetched once by
// exactly one block; store amp 1.08 measured).
// B: whole-K in bf16 REGISTERS (64 VGPR), pinned. Round 12 failed because
//    __launch_bounds__(256,4) capped VGPR at 128 -> allocator spilled B to
//    scratch (VGPR_Count=64 was the tell). Now (256,3) -> cap ~170.
// A: 16-row full-K chunks via 3-buffer rolling LDS (48 KB), staged 2 chunks
//    ahead by global_load_lds DMA -> ~2 chunk-times for L2 DMA to land.
// Sync: counted vmcnt + raw s_barrier; stores ride across barriers.
__global__ __launch_bounds__(256, 3) void gate_gemm(GemmParams P,
                                                    const unsigned short* __restrict__ embw,
                                                    float* __restrict__ out)
{
    constexpr int kStarts[11] = {0, 1728, 1792, 38656, 38720, 75584,
                                 75648, 112512, 112576, 120576, 120581};
    __shared__ unsigned short Atile[3][CH * GATE];   // 3 x 16 KB

    const int t    = threadIdx.x;
    const int lane = t & 63;
    const int wave = t >> 6;
    const int lr   = lane & 15;   // frag col (B/C) / frag row (A)
    const int lg   = lane >> 4;   // k-group / C row-group

    // This lane's single output column
    const int  n       = blockIdx.x * 64 + wave * 16 + lr;
    const bool valid   = n < NTOT;
    const bool wstores = (blockIdx.x * 64 + wave * 16) < NTOT;  // wave-uniform:
                                                                // does this wave issue stores?
    const int  nc    = valid ? n : NTOT - 1;
    int tt = 0;
#pragma unroll
    for (int i = 1; i < 10; ++i) tt += (nc >= kStarts[i]);
    const int rr = nc - kStarts[tt];
    const float* wrow = P.W[tt] + (size_t)rr * GATE + lg * 8;
    const float pv = P.p[tt][rr];
    const float bv = P.bias[tt][rr];

    // ---- A staging: chunk c = rows [c*16,+16), full K, swizzled.
    // LDS 16B-unit (row=i*4+wave, slotw=lane) holds
    // embw[c*16+row][(lane ^ (row&7))*8 .. +8]; read slot = (ks*4+lg)^(lr&7).
    auto stage = [&](int buf, int c) {
#pragma unroll
        for (int i = 0; i < 4; ++i) {
            const int rl = i * 4 + wave;
            const unsigned short* src =
                embw + (size_t)(c * CH + rl) * GATE + ((lane ^ (rl & 7)) * 8);
            unsigned short* dst = &Atile[buf][(size_t)(i * 256 + t) * 8];
            __builtin_amdgcn_global_load_lds(
                (const __attribute__((address_space(1))) void*)src,
                (__attribute__((address_space(3))) void*)dst, 16, 0, 0);
        }
    };

    stage(0, 0);   // chunks 0 and 1 stream while B prologue runs
    stage(1, 1);

    // ---- B prologue: whole-K B for this lane's column -> 16 x short8 (64 VGPR).
    // Batches of 2 frags keep raw-f32 pressure at 16 VGPR.
    short8 Bbf[16];
#pragma unroll
    for (int b = 0; b < 8; ++b) {
        f32x4 r0 = *(const f32x4*)(wrow + b * 64);
        f32x4 r1 = *(const f32x4*)(wrow + b * 64 + 4);
        f32x4 r2 = *(const f32x4*)(wrow + b * 64 + 32);
        f32x4 r3 = *(const f32x4*)(wrow + b * 64 + 36);
        short8 b0, b1;
#pragma unroll
        for (int q = 0; q < 4; ++q) {
            b0[q] = bf16bits(r0[q]); b0[4 + q] = bf16bits(r1[q]);
            b1[q] = bf16bits(r2[q]); b1[4 + q] = bf16bits(r3[q]);
        }
        Bbf[2 * b]     = b0;
        Bbf[2 * b + 1] = b1;
    }
    // PIN: opaque redefinition -> no remat; with cap~170 this stays in VGPRs.
#pragma unroll
    for (int i = 0; i < 16; ++i)
        asm volatile("" : "+v"(Bbf[i]));

    asm volatile("s_waitcnt vmcnt(0)" ::: "memory");   // prologue-only full drain
    __builtin_amdgcn_s_barrier();

#pragma unroll
    for (int c = 0; c < NCH; ++c) {
        const int buf = c % 3;
        if (c + 2 < NCH) stage((c + 2) % 3, c + 2);   // 4 VMEM, lands over 2 chunks

        // Two parallel 8-deep MFMA chains; zero global reads in the loop.
        f32x4 acc0 = (f32x4){0.f, 0.f, 0.f, 0.f};
        f32x4 acc1 = (f32x4){0.f, 0.f, 0.f, 0.f};
#pragma unroll
        for (int ks = 0; ks < 16; ++ks) {
            const int slot = (ks * 4 + lg) ^ (lr & 7);
            short8 af = *(const short8*)(&Atile[buf][lr * GATE + slot * 8]);
            if (ks & 1) acc1 = __builtin_amdgcn_mfma_f32_16x16x32_bf16(af, Bbf[ks], acc1, 0, 0, 0);
            else        acc0 = __builtin_amdgcn_mfma_f32_16x16x32_bf16(af, Bbf[ks], acc0, 0, 0, 0);
        }

        // Stores before the wait; they stay in flight across the barrier.
        if (valid) {
            float* ocol = out + n;
            const int m0 = c * CH + lg * 4;
#pragma unroll
            for (int q = 0; q < 4; ++q) {
                float x   = acc0[q] + acc1[q] + bv;
                float e   = __expf(-x);
                float eta = __builtin_amdgcn_rcpf(1.0f + e);
                ocol[(size_t)(m0 + q) * NTOT] = eta * pv;
            }
        }

        if (c + 1 < NCH) {
            if (c < NCH - 2) {
                // Ledger (in-order, store-issuing waves):
                //   [.., S(c+1)4, st(c-1)4, S(c+2)4, st(c)4] -> retire through
                //   S(c+1) => 12 left. Storeless waves: [S(c+1)4, S(c+2)4] -> 4.
                if (wstores) asm volatile("s_waitcnt vmcnt(12)" ::: "memory");
                else         asm volatile("s_waitcnt vmcnt(4)"  ::: "memory");
            } else {
                asm volatile("s_waitcnt vmcnt(0)" ::: "memory");  // once, c==14
            }
            __builtin_amdgcn_s_barrier();
            __builtin_amdgcn_sched_barrier(0);
        }
    }
}

extern "C" void kernel_launch(void* const* d_in, const int* in_sizes, int n_in,
                              void* d_out, int out_size, void* d_ws, size_t ws_size,
                              hipStream_t stream) {
    const float* emb = (const float*)d_in[0];
    GemmParams P;
    for (int i = 0; i < 10; ++i) {
        P.p[i]    = (const float*)d_in[1 + 3 * i];
        P.W[i]    = (const float*)d_in[2 + 3 * i];
        P.bias[i] = (const float*)d_in[3 + 3 * i];
    }

    unsigned short* embw = (unsigned short*)d_ws;   // 256 KB, L2-resident
    emb_to_bf16<<<(MROWS * GATE) / (256 * 8), 256, 0, stream>>>(emb, embw);

    int nblocks = (NTOT + 63) / 64;   // 1885
    gate_gemm<<<nblocks, 256, 0, stream>>>(P, embw, (float*)d_out);
}